// Round 1
// baseline (297.806 us; speedup 1.0000x reference)
//
#include <hip/hip_runtime.h>
#include <hip/hip_bf16.h>
#include <cstdint>

// LSTM cell: B=8192, D=1024, U=1024.
// z = [X|H](8192x2048) @ Wcat(2048x4096), gates interleaved in N (col 4u+g),
// fused epilogue computes c,h.

using f32x4  = __attribute__((ext_vector_type(4))) float;
using short8 = __attribute__((ext_vector_type(8))) short;

__device__ __forceinline__ unsigned short f2bf(float f) {
  union { float f; unsigned int u; } v; v.f = f;
  unsigned int r = v.u + 0x7fffu + ((v.u >> 16) & 1u);  // RNE
  return (unsigned short)(r >> 16);
}

// ---------- A conversion: Abf[b][k] = bf16(k<1024 ? X[b][k] : H[b][k-1024])
__global__ void conv_a_kernel(const float* __restrict__ X, const float* __restrict__ H,
                              unsigned short* __restrict__ Abf) {
  int idx = blockIdx.x * blockDim.x + threadIdx.x;  // 8192*1024/4 threads
  int b  = idx >> 8;
  int kq = (idx & 255) << 2;
  float4 x = *(const float4*)(X + (long)b * 1024 + kq);
  float4 h = *(const float4*)(H + (long)b * 1024 + kq);
  ushort4 xo, ho;
  xo.x = f2bf(x.x); xo.y = f2bf(x.y); xo.z = f2bf(x.z); xo.w = f2bf(x.w);
  ho.x = f2bf(h.x); ho.y = f2bf(h.y); ho.z = f2bf(h.z); ho.w = f2bf(h.w);
  *(ushort4*)(Abf + (long)b * 2048 + kq)        = xo;
  *(ushort4*)(Abf + (long)b * 2048 + 1024 + kq) = ho;
}

// ---------- B conversion: Bt[n=4u+g][k] = bf16(Wg[k][u] / Ug[k-1024][u]), N-major
__global__ void conv_b_kernel(const float* W_i, const float* U_i,
                              const float* W_f, const float* U_f,
                              const float* W_c, const float* U_c,
                              const float* W_o, const float* U_o,
                              unsigned short* __restrict__ Bt) {
  __shared__ float tile[64][65];  // +1 pad vs bank conflicts
  int z = blockIdx.z;
  const float* src;
  switch (z) {
    case 0: src = W_i; break; case 1: src = U_i; break;
    case 2: src = W_f; break; case 3: src = U_f; break;
    case 4: src = W_c; break; case 5: src = U_c; break;
    case 6: src = W_o; break; default: src = U_o; break;
  }
  int g = z >> 1, s = z & 1;
  int k0 = blockIdx.x * 64;
  int u0 = blockIdx.y * 64;
  int t = threadIdx.x;
  int c = t & 63, r0 = t >> 6;
#pragma unroll
  for (int i = 0; i < 16; ++i) {
    int r = i * 4 + r0;
    tile[r][c] = src[(long)(k0 + r) * 1024 + u0 + c];
  }
  __syncthreads();
  int ul = t >> 2;
  int ks = (t & 3) * 16;
  unsigned short outv[16];
#pragma unroll
  for (int j = 0; j < 16; ++j) outv[j] = f2bf(tile[ks + j][ul]);
  long n   = 4L * (u0 + ul) + g;
  long col = (long)s * 1024 + k0 + ks;
  uint4* dst = (uint4*)(Bt + n * 2048 + col);
  dst[0] = *(uint4*)(outv);
  dst[1] = *(uint4*)(outv + 8);
}

// ---------- bias interleave: biasc[4u+g] = b_g[u]
__global__ void conv_bias_kernel(const float* b_i, const float* b_f,
                                 const float* b_c, const float* b_o,
                                 float* __restrict__ biasc) {
  int n = blockIdx.x * blockDim.x + threadIdx.x;  // 4096
  int g = n & 3, u = n >> 2;
  float v = (g == 0) ? b_i[u] : (g == 1) ? b_f[u] : (g == 2) ? b_c[u] : b_o[u];
  biasc[n] = v;
}

// ---------- fused GEMM + LSTM epilogue
// 128x128 tile, BK=32, 4 waves (each 64x64 via 4x4 16x16x32 MFMA fragments).
__global__ __launch_bounds__(256) void lstm_gemm_kernel(
    const unsigned short* __restrict__ Abf,   // [8192][2048] bf16
    const unsigned short* __restrict__ Btbf,  // [4096][2048] bf16 (N-major)
    const float* __restrict__ biasc,          // [4096]
    const float* __restrict__ c_tm1,          // [8192][1024]
    float* __restrict__ outH, float* __restrict__ outC) {
  __shared__ unsigned short Als[2][128 * 32];
  __shared__ unsigned short Bls[2][128 * 32];

  int bid = blockIdx.x;
  int swz = (bid & 7) * 256 + (bid >> 3);  // XCD swizzle, 2048 % 8 == 0
  int bm = swz >> 5;  // 64 m-blocks
  int bn = swz & 31;  // 32 n-blocks

  int t = threadIdx.x;
  int lane = t & 63;
  int w = t >> 6;
  int wm = w >> 1, wn = w & 1;

  int arow = t >> 2;          // 0..63
  int acol = (t & 3) * 8;
  const unsigned short* gA0 = Abf  + ((long)(bm * 128 + arow) * 2048 + acol);
  const unsigned short* gA1 = gA0 + 64L * 2048;
  const unsigned short* gB0 = Btbf + ((long)(bn * 128 + arow) * 2048 + acol);
  const unsigned short* gB1 = gB0 + 64L * 2048;

  f32x4 acc[4][4];
#pragma unroll
  for (int mi = 0; mi < 4; ++mi)
#pragma unroll
    for (int ni = 0; ni < 4; ++ni) acc[mi][ni] = (f32x4){0.f, 0.f, 0.f, 0.f};

  int kgrp = lane >> 4;
  int rl = lane & 15;

#define STAGE(buf, k0)                                                                              \
  do {                                                                                              \
    __builtin_amdgcn_global_load_lds((const __attribute__((address_space(1))) void*)(gA0 + (k0)),   \
        (__attribute__((address_space(3))) void*)(&Als[buf][t * 8]), 16, 0, 0);                     \
    __builtin_amdgcn_global_load_lds((const __attribute__((address_space(1))) void*)(gA1 + (k0)),   \
        (__attribute__((address_space(3))) void*)(&Als[buf][2048 + t * 8]), 16, 0, 0);              \
    __builtin_amdgcn_global_load_lds((const __attribute__((address_space(1))) void*)(gB0 + (k0)),   \
        (__attribute__((address_space(3))) void*)(&Bls[buf][t * 8]), 16, 0, 0);                     \
    __builtin_amdgcn_global_load_lds((const __attribute__((address_space(1))) void*)(gB1 + (k0)),   \
        (__attribute__((address_space(3))) void*)(&Bls[buf][2048 + t * 8]), 16, 0, 0);              \
  } while (0)

  STAGE(0, 0);
  __syncthreads();

  int cur = 0;
  for (int kt = 0; kt < 64; ++kt) {
    if (kt < 63) STAGE(cur ^ 1, (kt + 1) * 32);
    const unsigned short* As = Als[cur];
    const unsigned short* Bs = Bls[cur];
    short8 af[4], bfr[4];
#pragma unroll
    for (int mi = 0; mi < 4; ++mi)
      af[mi] = *(const short8*)(As + (wm * 64 + mi * 16 + rl) * 32 + kgrp * 8);
#pragma unroll
    for (int ni = 0; ni < 4; ++ni)
      bfr[ni] = *(const short8*)(Bs + (wn * 64 + ni * 16 + rl) * 32 + kgrp * 8);
#pragma unroll
    for (int mi = 0; mi < 4; ++mi)
#pragma unroll
      for (int ni = 0; ni < 4; ++ni)
        acc[mi][ni] = __builtin_amdgcn_mfma_f32_16x16x32_bf16(af[mi], bfr[ni], acc[mi][ni], 0, 0, 0);
    __syncthreads();
    cur ^= 1;
  }
#undef STAGE

  // ---- fused LSTM epilogue ----
  // col n = nbase + ni*16 + (lane&15); gate = n&3 = lane&3; u = n>>2.
  // Quad lanes {g=0..3} hold gates i,f,c,o for the same (row,u).
  int mbase = bm * 128 + wm * 64;
  int nbase = bn * 128 + wn * 64;
#pragma unroll
  for (int mi = 0; mi < 4; ++mi) {
#pragma unroll
    for (int ni = 0; ni < 4; ++ni) {
      int n_g = nbase + ni * 16 + rl;
      float bias = biasc[n_g];
      int u = n_g >> 2;
#pragma unroll
      for (int j = 0; j < 4; ++j) {
        float zv = acc[mi][ni][j] + bias;
        float z1 = __shfl_xor(zv, 1, 64);
        float z2 = __shfl_xor(zv, 2, 64);
        float z3 = __shfl_xor(z1, 2, 64);
        if ((lane & 3) == 0) {
          // lane g==0: zv=zi, z1=zf, z2=zc, z3=zo
          int brow = mbase + mi * 16 + ((lane >> 4) << 2) + j;
          float ig = 1.f / (1.f + __expf(-zv));
          float fg = 1.f / (1.f + __expf(-z1));
          float cg = 1.f - 2.f / (__expf(2.f * z2) + 1.f);   // tanh
          float og = 1.f / (1.f + __expf(-z3));
          float cp = c_tm1[(long)brow * 1024 + u];
          float cn = fg * cp + ig * cg;
          float hn = og * (1.f - 2.f / (__expf(2.f * cn) + 1.f));
          outH[(long)brow * 1024 + u] = hn;
          outC[(long)brow * 1024 + u] = cn;
        }
      }
    }
  }
}

extern "C" void kernel_launch(void* const* d_in, const int* in_sizes, int n_in,
                              void* d_out, int out_size, void* d_ws, size_t ws_size,
                              hipStream_t stream) {
  (void)in_sizes; (void)n_in; (void)out_size; (void)ws_size;
  const float* X   = (const float*)d_in[0];
  const float* Hst = (const float*)d_in[1];
  const float* Cst = (const float*)d_in[2];
  const float* W_i = (const float*)d_in[3];
  const float* U_i = (const float*)d_in[4];
  const float* b_i = (const float*)d_in[5];
  const float* W_f = (const float*)d_in[6];
  const float* U_f = (const float*)d_in[7];
  const float* b_f = (const float*)d_in[8];
  const float* W_c = (const float*)d_in[9];
  const float* U_c = (const float*)d_in[10];
  const float* b_c = (const float*)d_in[11];
  const float* W_o = (const float*)d_in[12];
  const float* U_o = (const float*)d_in[13];
  const float* b_o = (const float*)d_in[14];

  unsigned short* Abf  = (unsigned short*)d_ws;                        // 32 MB
  unsigned short* Btbf = (unsigned short*)((char*)d_ws + 33554432);    // 16 MB
  float*          biasc = (float*)((char*)d_ws + 50331648);            // 16 KB

  float* outH = (float*)d_out;
  float* outC = outH + 8192L * 1024;

  conv_a_kernel<<<8192, 256, 0, stream>>>(X, Hst, Abf);
  conv_b_kernel<<<dim3(16, 16, 8), 256, 0, stream>>>(W_i, U_i, W_f, U_f, W_c, U_c, W_o, U_o, Btbf);
  conv_bias_kernel<<<16, 256, 0, stream>>>(b_i, b_f, b_c, b_o, biasc);
  lstm_gemm_kernel<<<2048, 256, 0, stream>>>(Abf, Btbf, biasc, Cst, outH, outC);
}

// Round 2
// 209.758 us; speedup vs baseline: 1.4198x; 1.4198x over previous
//
#include <hip/hip_runtime.h>
#include <hip/hip_bf16.h>
#include <cstdint>

// LSTM cell: B=8192, D=1024, U=1024.
// z = [X|H](8192x2048) @ Wcat(2048x4096), fused epilogue computes c,h.
// Gate interleave granularity 16: column n = (u>>4)*64 + g*16 + (u&15),
// so a 64-wide wave N-span holds gates i,f,c,o (ni=0..3) for the same 16 u's.

using f32x4  = __attribute__((ext_vector_type(4))) float;
using short8 = __attribute__((ext_vector_type(8))) short;

__device__ __forceinline__ unsigned short f2bf(float f) {
  union { float f; unsigned int u; } v; v.f = f;
  unsigned int r = v.u + 0x7fffu + ((v.u >> 16) & 1u);  // RNE
  return (unsigned short)(r >> 16);
}

__device__ __forceinline__ float sigmoidf_fast(float x) {
  return 1.f / (1.f + __expf(-x));
}
__device__ __forceinline__ float tanhf_fast(float x) {
  return 1.f - 2.f / (__expf(2.f * x) + 1.f);
}

// ---------- A conversion: Abf[b][k] = bf16(k<1024 ? X[b][k] : H[b][k-1024])
__global__ void conv_a_kernel(const float* __restrict__ X, const float* __restrict__ H,
                              unsigned short* __restrict__ Abf) {
  int idx = blockIdx.x * blockDim.x + threadIdx.x;  // 8192*256 threads
  int b  = idx >> 8;
  int kq = (idx & 255) << 2;
  float4 x = *(const float4*)(X + (long)b * 1024 + kq);
  float4 h = *(const float4*)(H + (long)b * 1024 + kq);
  ushort4 xo, ho;
  xo.x = f2bf(x.x); xo.y = f2bf(x.y); xo.z = f2bf(x.z); xo.w = f2bf(x.w);
  ho.x = f2bf(h.x); ho.y = f2bf(h.y); ho.z = f2bf(h.z); ho.w = f2bf(h.w);
  *(ushort4*)(Abf + (long)b * 2048 + kq)        = xo;
  *(ushort4*)(Abf + (long)b * 2048 + 1024 + kq) = ho;
}

// ---------- B conversion: Bt[n][k] bf16, N-major, n = (u>>4)*64 + g*16 + (u&15)
__global__ void conv_b_kernel(const float* W_i, const float* U_i,
                              const float* W_f, const float* U_f,
                              const float* W_c, const float* U_c,
                              const float* W_o, const float* U_o,
                              unsigned short* __restrict__ Bt) {
  __shared__ float tile[64][65];  // +1 pad vs bank conflicts
  int z = blockIdx.z;
  const float* src;
  switch (z) {
    case 0: src = W_i; break; case 1: src = U_i; break;
    case 2: src = W_f; break; case 3: src = U_f; break;
    case 4: src = W_c; break; case 5: src = U_c; break;
    case 6: src = W_o; break; default: src = U_o; break;
  }
  int g = z >> 1, s = z & 1;
  int k0 = blockIdx.x * 64;
  int u0 = blockIdx.y * 64;
  int t = threadIdx.x;
  int c = t & 63, r0 = t >> 6;
#pragma unroll
  for (int i = 0; i < 16; ++i) {
    int r = i * 4 + r0;
    tile[r][c] = src[(long)(k0 + r) * 1024 + u0 + c];
  }
  __syncthreads();
  int ul = t >> 2;            // 0..63, local u
  int ks = (t & 3) * 16;      // k sub-block
  unsigned short outv[16];
#pragma unroll
  for (int j = 0; j < 16; ++j) outv[j] = f2bf(tile[ks + j][ul]);
  long n   = 4L * u0 + (ul >> 4) * 64 + g * 16 + (ul & 15);
  long col = (long)s * 1024 + k0 + ks;
  uint4* dst = (uint4*)(Bt + n * 2048 + col);
  dst[0] = *(uint4*)(outv);
  dst[1] = *(uint4*)(outv + 8);
}

// ---------- fused GEMM + LSTM epilogue
// 128x128 tile, BK=32, 4 waves (each 64x64 via 4x4 16x16x32 MFMA fragments).
__global__ __launch_bounds__(256) void lstm_gemm_kernel(
    const unsigned short* __restrict__ Abf,   // [8192][2048] bf16
    const unsigned short* __restrict__ Btbf,  // [4096][2048] bf16 (N-major)
    const float* __restrict__ b_i, const float* __restrict__ b_f,
    const float* __restrict__ b_c, const float* __restrict__ b_o,
    const float* __restrict__ c_tm1,          // [8192][1024]
    float* __restrict__ outH, float* __restrict__ outC) {
  __shared__ unsigned short Als[2][128 * 32];
  __shared__ unsigned short Bls[2][128 * 32];

  int bid = blockIdx.x;
  int swz = (bid & 7) * 256 + (bid >> 3);  // XCD swizzle, 2048 % 8 == 0
  int bm = swz >> 5;  // 64 m-blocks
  int bn = swz & 31;  // 32 n-blocks

  int t = threadIdx.x;
  int lane = t & 63;
  int w = t >> 6;
  int wm = w >> 1, wn = w & 1;

  int arow = t >> 2;          // 0..63
  int acol = (t & 3) * 8;
  const unsigned short* gA0 = Abf  + ((long)(bm * 128 + arow) * 2048 + acol);
  const unsigned short* gA1 = gA0 + 64L * 2048;
  const unsigned short* gB0 = Btbf + ((long)(bn * 128 + arow) * 2048 + acol);
  const unsigned short* gB1 = gB0 + 64L * 2048;

  f32x4 acc[4][4];
#pragma unroll
  for (int mi = 0; mi < 4; ++mi)
#pragma unroll
    for (int ni = 0; ni < 4; ++ni) acc[mi][ni] = (f32x4){0.f, 0.f, 0.f, 0.f};

  int kgrp = lane >> 4;
  int rl = lane & 15;

#define STAGE(buf, k0)                                                                              \
  do {                                                                                              \
    __builtin_amdgcn_global_load_lds((const __attribute__((address_space(1))) void*)(gA0 + (k0)),   \
        (__attribute__((address_space(3))) void*)(&Als[buf][t * 8]), 16, 0, 0);                     \
    __builtin_amdgcn_global_load_lds((const __attribute__((address_space(1))) void*)(gA1 + (k0)),   \
        (__attribute__((address_space(3))) void*)(&Als[buf][2048 + t * 8]), 16, 0, 0);              \
    __builtin_amdgcn_global_load_lds((const __attribute__((address_space(1))) void*)(gB0 + (k0)),   \
        (__attribute__((address_space(3))) void*)(&Bls[buf][t * 8]), 16, 0, 0);                     \
    __builtin_amdgcn_global_load_lds((const __attribute__((address_space(1))) void*)(gB1 + (k0)),   \
        (__attribute__((address_space(3))) void*)(&Bls[buf][2048 + t * 8]), 16, 0, 0);              \
  } while (0)

  STAGE(0, 0);
  __syncthreads();

  int cur = 0;
  for (int kt = 0; kt < 64; ++kt) {
    if (kt < 63) STAGE(cur ^ 1, (kt + 1) * 32);
    const unsigned short* As = Als[cur];
    const unsigned short* Bs = Bls[cur];
    short8 af[4], bfr[4];
#pragma unroll
    for (int mi = 0; mi < 4; ++mi)
      af[mi] = *(const short8*)(As + (wm * 64 + mi * 16 + rl) * 32 + kgrp * 8);
#pragma unroll
    for (int ni = 0; ni < 4; ++ni)
      bfr[ni] = *(const short8*)(Bs + (wn * 64 + ni * 16 + rl) * 32 + kgrp * 8);
#pragma unroll
    for (int mi = 0; mi < 4; ++mi)
#pragma unroll
      for (int ni = 0; ni < 4; ++ni)
        acc[mi][ni] = __builtin_amdgcn_mfma_f32_16x16x32_bf16(af[mi], bfr[ni], acc[mi][ni], 0, 0, 0);
    __syncthreads();
    cur ^= 1;
  }
#undef STAGE

  // ---- fused LSTM epilogue ----
  // Wave N-span = 64 cols = one u-block: u = nbase/4 + rl; gate g = ni.
  // C/D layout: col = lane&15, row = (lane>>4)*4 + j.
  int mbase = bm * 128 + wm * 64;
  int nbase = bn * 128 + wn * 64;
  int u = (nbase >> 2) + rl;
  float bi_v = b_i[u], bf_v = b_f[u], bc_v = b_c[u], bo_v = b_o[u];
  int rquad = (lane >> 4) << 2;
#pragma unroll
  for (int mi = 0; mi < 4; ++mi) {
#pragma unroll
    for (int j = 0; j < 4; ++j) {
      int brow = mbase + mi * 16 + rquad + j;
      float zi = acc[mi][0][j] + bi_v;
      float zf = acc[mi][1][j] + bf_v;
      float zc = acc[mi][2][j] + bc_v;
      float zo = acc[mi][3][j] + bo_v;
      float ig = sigmoidf_fast(zi);
      float fg = sigmoidf_fast(zf);
      float cg = tanhf_fast(zc);
      float og = sigmoidf_fast(zo);
      float cp = c_tm1[(long)brow * 1024 + u];
      float cn = fg * cp + ig * cg;
      float hn = og * tanhf_fast(cn);
      outH[(long)brow * 1024 + u] = hn;
      outC[(long)brow * 1024 + u] = cn;
    }
  }
}

extern "C" void kernel_launch(void* const* d_in, const int* in_sizes, int n_in,
                              void* d_out, int out_size, void* d_ws, size_t ws_size,
                              hipStream_t stream) {
  (void)in_sizes; (void)n_in; (void)out_size; (void)ws_size;
  const float* X   = (const float*)d_in[0];
  const float* Hst = (const float*)d_in[1];
  const float* Cst = (const float*)d_in[2];
  const float* W_i = (const float*)d_in[3];
  const float* U_i = (const float*)d_in[4];
  const float* b_i = (const float*)d_in[5];
  const float* W_f = (const float*)d_in[6];
  const float* U_f = (const float*)d_in[7];
  const float* b_f = (const float*)d_in[8];
  const float* W_c = (const float*)d_in[9];
  const float* U_c = (const float*)d_in[10];
  const float* b_c = (const float*)d_in[11];
  const float* W_o = (const float*)d_in[12];
  const float* U_o = (const float*)d_in[13];
  const float* b_o = (const float*)d_in[14];

  unsigned short* Abf  = (unsigned short*)d_ws;                        // 32 MB
  unsigned short* Btbf = (unsigned short*)((char*)d_ws + 33554432);    // 16 MB

  float* outH = (float*)d_out;
  float* outC = outH + 8192L * 1024;

  conv_a_kernel<<<8192, 256, 0, stream>>>(X, Hst, Abf);
  conv_b_kernel<<<dim3(16, 16, 8), 256, 0, stream>>>(W_i, U_i, W_f, U_f, W_c, U_c, W_o, U_o, Btbf);
  lstm_gemm_kernel<<<2048, 256, 0, stream>>>(Abf, Btbf, b_i, b_f, b_c, b_o, Cst, outH, outC);
}

// Round 3
// 164.390 us; speedup vs baseline: 1.8116x; 1.2760x over previous
//
#include <hip/hip_runtime.h>
#include <hip/hip_bf16.h>
#include <cstdint>

// LSTM cell: B=8192, D=1024, U=1024.
// z = [X|H](8192x2048) @ Wcat(2048x4096), gate interleave 16 in N, fused epilogue.
// GEMM: 256x256 tile, BK=32, 8 waves (2Mx4N), 512 thr, triple-buffered LDS,
// 2 phases/K-tile with counted vmcnt(4) (T3+T4), setprio (T5), XOR swizzle (T2).

using f32x4  = __attribute__((ext_vector_type(4))) float;
using short8 = __attribute__((ext_vector_type(8))) short;

__device__ __forceinline__ unsigned short f2bf(float f) {
  union { float f; unsigned int u; } v; v.f = f;
  unsigned int r = v.u + 0x7fffu + ((v.u >> 16) & 1u);  // RNE
  return (unsigned short)(r >> 16);
}
__device__ __forceinline__ float sigmoidf_fast(float x) { return 1.f / (1.f + __expf(-x)); }
__device__ __forceinline__ float tanhf_fast(float x)    { return 1.f - 2.f / (__expf(2.f * x) + 1.f); }

// ---------- A conversion: Abf[b][k] = bf16(k<1024 ? X[b][k] : H[b][k-1024])
__global__ void conv_a_kernel(const float* __restrict__ X, const float* __restrict__ H,
                              unsigned short* __restrict__ Abf) {
  int idx = blockIdx.x * blockDim.x + threadIdx.x;
  int b  = idx >> 8;
  int kq = (idx & 255) << 2;
  float4 x = *(const float4*)(X + (long)b * 1024 + kq);
  float4 h = *(const float4*)(H + (long)b * 1024 + kq);
  ushort4 xo, ho;
  xo.x = f2bf(x.x); xo.y = f2bf(x.y); xo.z = f2bf(x.z); xo.w = f2bf(x.w);
  ho.x = f2bf(h.x); ho.y = f2bf(h.y); ho.z = f2bf(h.z); ho.w = f2bf(h.w);
  *(ushort4*)(Abf + (long)b * 2048 + kq)        = xo;
  *(ushort4*)(Abf + (long)b * 2048 + 1024 + kq) = ho;
}

// ---------- B conversion: Bt[n][k] bf16, N-major, n = (u>>4)*64 + g*16 + (u&15)
__global__ void conv_b_kernel(const float* W_i, const float* U_i,
                              const float* W_f, const float* U_f,
                              const float* W_c, const float* U_c,
                              const float* W_o, const float* U_o,
                              unsigned short* __restrict__ Bt) {
  __shared__ float tile[64][65];
  int z = blockIdx.z;
  const float* src;
  switch (z) {
    case 0: src = W_i; break; case 1: src = U_i; break;
    case 2: src = W_f; break; case 3: src = U_f; break;
    case 4: src = W_c; break; case 5: src = U_c; break;
    case 6: src = W_o; break; default: src = U_o; break;
  }
  int g = z >> 1, s = z & 1;
  int k0 = blockIdx.x * 64;
  int u0 = blockIdx.y * 64;
  int t = threadIdx.x;
  int c = t & 63, r0 = t >> 6;
#pragma unroll
  for (int i = 0; i < 16; ++i) {
    int r = i * 4 + r0;
    tile[r][c] = src[(long)(k0 + r) * 1024 + u0 + c];
  }
  __syncthreads();
  int ul = t >> 2;
  int ks = (t & 3) * 16;
  unsigned short outv[16];
#pragma unroll
  for (int j = 0; j < 16; ++j) outv[j] = f2bf(tile[ks + j][ul]);
  long n   = 4L * u0 + (ul >> 4) * 64 + g * 16 + (ul & 15);
  long col = (long)s * 1024 + k0 + ks;
  uint4* dst = (uint4*)(Bt + n * 2048 + col);
  dst[0] = *(uint4*)(outv);
  dst[1] = *(uint4*)(outv + 8);
}

// ---------- fused GEMM + LSTM epilogue, 256x256 tile, 8-wave phase schedule
__global__ __launch_bounds__(512) void lstm_gemm_kernel(
    const unsigned short* __restrict__ Abf,   // [8192][2048] bf16
    const unsigned short* __restrict__ Btbf,  // [4096][2048] bf16 (N-major)
    const float* __restrict__ b_i, const float* __restrict__ b_f,
    const float* __restrict__ b_c, const float* __restrict__ b_o,
    const float* __restrict__ c_tm1,
    float* __restrict__ outH, float* __restrict__ outC) {
  // 3 buffers x (A tile 256x32 + B tile 256x32) bf16 = 3 x 32KB = 96KB
  __shared__ unsigned short smem[3 * 16384];

  int bid = blockIdx.x;
  int swz = (bid & 7) * 64 + (bid >> 3);  // XCD swizzle, 512 % 8 == 0
  int bm = swz >> 4;   // 32 m-blocks
  int bn = swz & 15;   // 16 n-blocks

  int t = threadIdx.x;
  int lane = t & 63;
  int w = t >> 6;           // 8 waves
  int wm = w >> 2;          // 0..1
  int wn = w & 3;           // 0..3
  int rl = lane & 15;
  int kg = lane >> 4;       // 0..3, 8-elem k-chunk

  // ---- ds_read element offsets (XOR chunk swizzle: chunk ^= (row>>1)&3) ----
#define AOFF(MI) ((wm * 128 + (MI) * 16 + rl) * 32 + \
    ((((kg * 16) ^ ((((wm * 128 + (MI) * 16 + rl) >> 1) & 3) << 4))) >> 1))
#define BOFF(NI) ((wn * 64 + (NI) * 16 + rl) * 32 + \
    ((((kg * 16) ^ ((((wn * 64 + (NI) * 16 + rl) >> 1) & 3) << 4))) >> 1))
  const int offA0 = AOFF(0), offA1 = AOFF(1), offA2 = AOFF(2), offA3 = AOFF(3);
  const int offA4 = AOFF(4), offA5 = AOFF(5), offA6 = AOFF(6), offA7 = AOFF(7);
  const int offB0 = 8192 + BOFF(0), offB1 = 8192 + BOFF(1);
  const int offB2 = 8192 + BOFF(2), offB3 = 8192 + BOFF(3);
#undef AOFF
#undef BOFF

  // ---- staging: linear LDS dest, inverse-swizzled global source ----
  int srow = t >> 2;                       // 0..127 (+128 for second load)
  int cbe  = (((t & 3) * 16) ^ (((srow >> 1) & 3) << 4)) >> 1;  // src k-elem offset
  const unsigned short* aS0 = Abf  + (long)(bm * 256 + srow) * 2048 + cbe;
  const unsigned short* aS1 = aS0 + 128L * 2048;
  const unsigned short* bS0 = Btbf + (long)(bn * 256 + srow) * 2048 + cbe;
  const unsigned short* bS1 = bS0 + 128L * 2048;
  const int dstA0 = t * 8, dstA1 = 4096 + t * 8;
  const int dstB0 = 8192 + t * 8, dstB1 = 12288 + t * 8;

#define GLL(SRC, SB, DOFF)                                                                     \
  __builtin_amdgcn_global_load_lds((const __attribute__((address_space(1))) void*)(SRC),       \
      (__attribute__((address_space(3))) void*)(&smem[(SB) * 16384 + (DOFF)]), 16, 0, 0)

  f32x4 acc[8][4];
#pragma unroll
  for (int mi = 0; mi < 8; ++mi)
#pragma unroll
    for (int ni = 0; ni < 4; ++ni) acc[mi][ni] = (f32x4){0.f, 0.f, 0.f, 0.f};

  // ---- prologue: stage tiles 0,1; drain tile 0 only (counted) ----
  GLL(aS0, 0, dstA0); GLL(aS1, 0, dstA1); GLL(bS0, 0, dstB0); GLL(bS1, 0, dstB1);
  GLL(aS0 + 32, 1, dstA0); GLL(aS1 + 32, 1, dstA1);
  GLL(bS0 + 32, 1, dstB0); GLL(bS1 + 32, 1, dstB1);
  asm volatile("s_waitcnt vmcnt(4)" ::: "memory");
  __builtin_amdgcn_s_barrier();
  aS0 += 64; aS1 += 64; bS0 += 64; bS1 += 64;   // point at tile 2

#define MF_ROW(AF, MI)                                                                  \
  acc[MI][0] = __builtin_amdgcn_mfma_f32_16x16x32_bf16(AF, bfr0, acc[MI][0], 0, 0, 0);  \
  acc[MI][1] = __builtin_amdgcn_mfma_f32_16x16x32_bf16(AF, bfr1, acc[MI][1], 0, 0, 0);  \
  acc[MI][2] = __builtin_amdgcn_mfma_f32_16x16x32_bf16(AF, bfr2, acc[MI][2], 0, 0, 0);  \
  acc[MI][3] = __builtin_amdgcn_mfma_f32_16x16x32_bf16(AF, bfr3, acc[MI][3], 0, 0, 0);

#define ITER(RBUF, SBUF, KOFF, DOSTAGE, VMN)                                   \
  do {                                                                         \
    const unsigned short* As_ = smem + (RBUF) * 16384;                         \
    /* phase 1: B frags + A frags mi0-3, stage A of tile+2 */                  \
    short8 bfr0 = *(const short8*)(As_ + offB0);                               \
    short8 bfr1 = *(const short8*)(As_ + offB1);                               \
    short8 bfr2 = *(const short8*)(As_ + offB2);                               \
    short8 bfr3 = *(const short8*)(As_ + offB3);                               \
    short8 a0_ = *(const short8*)(As_ + offA0);                                \
    short8 a1_ = *(const short8*)(As_ + offA1);                                \
    short8 a2_ = *(const short8*)(As_ + offA2);                                \
    short8 a3_ = *(const short8*)(As_ + offA3);                                \
    if (DOSTAGE) { GLL(aS0 + (KOFF), (SBUF), dstA0); GLL(aS1 + (KOFF), (SBUF), dstA1); } \
    __builtin_amdgcn_s_barrier();                                              \
    asm volatile("s_waitcnt lgkmcnt(0)" ::: "memory");                         \
    __builtin_amdgcn_sched_barrier(0);                                         \
    __builtin_amdgcn_s_setprio(1);                                             \
    MF_ROW(a0_, 0) MF_ROW(a1_, 1) MF_ROW(a2_, 2) MF_ROW(a3_, 3)                \
    __builtin_amdgcn_s_setprio(0);                                             \
    __builtin_amdgcn_sched_barrier(0);                                         \
    __builtin_amdgcn_s_barrier();                                              \
    /* phase 2: A frags mi4-7, stage B of tile+2, counted vmcnt */             \
    short8 a4_ = *(const short8*)(As_ + offA4);                                \
    short8 a5_ = *(const short8*)(As_ + offA5);                                \
    short8 a6_ = *(const short8*)(As_ + offA6);                                \
    short8 a7_ = *(const short8*)(As_ + offA7);                                \
    if (DOSTAGE) { GLL(bS0 + (KOFF), (SBUF), dstB0); GLL(bS1 + (KOFF), (SBUF), dstB1); } \
    if ((VMN) == 4) asm volatile("s_waitcnt vmcnt(4)" ::: "memory");           \
    if ((VMN) == 0) asm volatile("s_waitcnt vmcnt(0)" ::: "memory");           \
    __builtin_amdgcn_s_barrier();                                              \
    asm volatile("s_waitcnt lgkmcnt(0)" ::: "memory");                         \
    __builtin_amdgcn_sched_barrier(0);                                         \
    __builtin_amdgcn_s_setprio(1);                                             \
    MF_ROW(a4_, 4) MF_ROW(a5_, 5) MF_ROW(a6_, 6) MF_ROW(a7_, 7)                \
    __builtin_amdgcn_s_setprio(0);                                             \
    __builtin_amdgcn_sched_barrier(0);                                         \
    __builtin_amdgcn_s_barrier();                                              \
  } while (0)

  // 64 K-tiles total. Main: T=0..59 (20 groups of 3), tail T=60..63.
  for (int g = 0; g < 20; ++g) {
    ITER(0, 2, 0,  1, 4);
    ITER(1, 0, 32, 1, 4);
    ITER(2, 1, 64, 1, 4);
    aS0 += 96; aS1 += 96; bS0 += 96; bS1 += 96;
  }
  ITER(0, 2, 0,  1, 4);    // T=60: stages tile 62 -> buf 2
  ITER(1, 0, 32, 1, 4);    // T=61: stages tile 63 -> buf 0
  ITER(2, 0, 0,  0, 0);    // T=62: no stage, drain all (tile 63 ready)
  ITER(0, 0, 0,  0, -1);   // T=63
#undef ITER
#undef MF_ROW
#undef GLL

  // ---- fused LSTM epilogue ----
  // Wave N-span = 64 cols = one u-block: u = nbase/4 + rl; gate = ni.
  int mbase = bm * 256 + wm * 128;
  int nbase = bn * 256 + wn * 64;
  int u = (nbase >> 2) + rl;
  float bi_v = b_i[u], bf_v = b_f[u], bc_v = b_c[u], bo_v = b_o[u];
  int rquad = (lane >> 4) << 2;
#pragma unroll
  for (int mi = 0; mi < 8; ++mi) {
#pragma unroll
    for (int j = 0; j < 4; ++j) {
      int brow = mbase + mi * 16 + rquad + j;
      float zi = acc[mi][0][j] + bi_v;
      float zf = acc[mi][1][j] + bf_v;
      float zc = acc[mi][2][j] + bc_v;
      float zo = acc[mi][3][j] + bo_v;
      float ig = sigmoidf_fast(zi);
      float fg = sigmoidf_fast(zf);
      float cg = tanhf_fast(zc);
      float og = sigmoidf_fast(zo);
      float cp = c_tm1[(long)brow * 1024 + u];
      float cn = fg * cp + ig * cg;
      float hn = og * tanhf_fast(cn);
      outH[(long)brow * 1024 + u] = hn;
      outC[(long)brow * 1024 + u] = cn;
    }
  }
}

extern "C" void kernel_launch(void* const* d_in, const int* in_sizes, int n_in,
                              void* d_out, int out_size, void* d_ws, size_t ws_size,
                              hipStream_t stream) {
  (void)in_sizes; (void)n_in; (void)out_size; (void)ws_size;
  const float* X   = (const float*)d_in[0];
  const float* Hst = (const float*)d_in[1];
  const float* Cst = (const float*)d_in[2];
  const float* W_i = (const float*)d_in[3];
  const float* U_i = (const float*)d_in[4];
  const float* b_i = (const float*)d_in[5];
  const float* W_f = (const float*)d_in[6];
  const float* U_f = (const float*)d_in[7];
  const float* b_f = (const float*)d_in[8];
  const float* W_c = (const float*)d_in[9];
  const float* U_c = (const float*)d_in[10];
  const float* b_c = (const float*)d_in[11];
  const float* W_o = (const float*)d_in[12];
  const float* U_o = (const float*)d_in[13];
  const float* b_o = (const float*)d_in[14];

  unsigned short* Abf  = (unsigned short*)d_ws;                        // 32 MB
  unsigned short* Btbf = (unsigned short*)((char*)d_ws + 33554432);    // 16 MB

  float* outH = (float*)d_out;
  float* outC = outH + 8192L * 1024;

  conv_a_kernel<<<8192, 256, 0, stream>>>(X, Hst, Abf);
  conv_b_kernel<<<dim3(16, 16, 8), 256, 0, stream>>>(W_i, U_i, W_f, U_f, W_c, U_c, W_o, U_o, Btbf);
  lstm_gemm_kernel<<<512, 512, 0, stream>>>(Abf, Btbf, b_i, b_f, b_c, b_o, Cst, outH, outC);
}